// Round 5
// baseline (404.160 us; speedup 1.0000x reference)
//
#include <hip/hip_runtime.h>

// DBASolver: B=16, N=196608, C=2.
// Pass 1: per-batch reduction of H_eff (21 sym) + g_eff (6), Schur fused,
//         ALSO stashes per-point [inv*gd, inv*h[0..5]] (32 B) into d_ws.
// Pass 2: 16x 6x6 Gauss-Jordan solves.
// Pass 3: delta_depth = stash.s0 - stash.sv . dp  (reads 101 MB stash,
//         NOT the 226 MB input again).
//
// R3 finding: read rate pinned at ~2.5 TB/s across AoS/coalesced/LDS-staged
// variants -> cached-read-path cap, not access pattern. R4 fix: the
// nontemporal builtins need clang ext_vector_type, not HIP_vector_type.

typedef float fv4 __attribute__((ext_vector_type(4)));
typedef float fv2 __attribute__((ext_vector_type(2)));

constexpr int NACC = 27;  // 21 upper-triangular H entries + 6 g entries

template <bool STASH>
__device__ __forceinline__ void accum_point_stash(
    const float* __restrict__ ja, const float* __restrict__ jb,
    float r0, float r1, float conf, float nlam, float jd0, float jd1,
    float lam, float* __restrict__ A, float* __restrict__ g,
    fv4* __restrict__ st)
{
    float h[6], gp[6];
#pragma unroll
    for (int i = 0; i < 6; ++i) {
        h[i]  = conf * (ja[i] * jd0 + jb[i] * jd1);   // H_pd[b,n,i]
        gp[i] = conf * (ja[i] * r0 + jb[i] * r1);     // g_p contribution
    }
    const float hdd = conf * (jd0 * jd0 + jd1 * jd1);
    const float inv = 1.0f / fmaxf(hdd + lam + nlam, 1e-4f);
    const float gd  = conf * (jd0 * r0 + jd1 * r1);
    const float gdinv = gd * inv;
    float sv[6];
#pragma unroll
    for (int i = 0; i < 6; ++i) sv[i] = h[i] * inv;
    if (STASH) {
        st[0] = (fv4){gdinv, sv[0], sv[1], sv[2]};
        st[1] = (fv4){sv[3], sv[4], sv[5], 0.f};
    }
    int idx = 0;
#pragma unroll
    for (int i = 0; i < 6; ++i) {
#pragma unroll
        for (int j = i; j < 6; ++j) {
            A[idx] += conf * (ja[i] * ja[j] + jb[i] * jb[j]) - sv[i] * h[j];
            ++idx;
        }
        g[i] += gp[i] - h[i] * gdinv;
    }
}

template <bool STASH>
__global__ __launch_bounds__(256) void dba_reduce_k(
    const float* __restrict__ r, const float* __restrict__ w,
    const float* __restrict__ J_p, const float* __restrict__ J_d,
    const float* __restrict__ lmbda, float* __restrict__ acc,
    float* __restrict__ stash, int N)
{
    const int b = blockIdx.y;
    const float lam = lmbda[b];
    float A[21], g[6];
#pragma unroll
    for (int i = 0; i < 21; ++i) A[i] = 0.f;
#pragma unroll
    for (int i = 0; i < 6; ++i) g[i] = 0.f;

    const size_t base = (size_t)b * (size_t)N;
    const int P = N >> 1;
    const int stride = gridDim.x * blockDim.x;
    for (int pr = blockIdx.x * blockDim.x + threadIdx.x; pr < P; pr += stride) {
        const size_t p = base + (size_t)(pr << 1);
        const fv4 rv = __builtin_nontemporal_load((const fv4*)(r + p * 2));
        const fv4 wv = __builtin_nontemporal_load((const fv4*)(w + p * 2));
        const fv4 jd = __builtin_nontemporal_load((const fv4*)(J_d + p * 2));
        const fv4* jp = (const fv4*)(J_p + p * 12);
        const fv4 q0 = __builtin_nontemporal_load(jp + 0);
        const fv4 q1 = __builtin_nontemporal_load(jp + 1);
        const fv4 q2 = __builtin_nontemporal_load(jp + 2);
        const fv4 q3 = __builtin_nontemporal_load(jp + 3);
        const fv4 q4 = __builtin_nontemporal_load(jp + 4);
        const fv4 q5 = __builtin_nontemporal_load(jp + 5);

        fv4 st[4];
        {
            const float ja[6] = {q0.x, q0.y, q0.z, q0.w, q1.x, q1.y};
            const float jb[6] = {q1.z, q1.w, q2.x, q2.y, q2.z, q2.w};
            accum_point_stash<STASH>(ja, jb, rv.x, rv.y, wv.x, wv.y,
                                     jd.x, jd.y, lam, A, g, st);
        }
        {
            const float ja[6] = {q3.x, q3.y, q3.z, q3.w, q4.x, q4.y};
            const float jb[6] = {q4.z, q4.w, q5.x, q5.y, q5.z, q5.w};
            accum_point_stash<STASH>(ja, jb, rv.z, rv.w, wv.z, wv.w,
                                     jd.z, jd.w, lam, A, g, st + 2);
        }
        if (STASH) {
            fv4* sp = (fv4*)(stash + p * 8);
            __builtin_nontemporal_store(st[0], sp + 0);
            __builtin_nontemporal_store(st[1], sp + 1);
            __builtin_nontemporal_store(st[2], sp + 2);
            __builtin_nontemporal_store(st[3], sp + 3);
        }
    }

    float v[NACC];
#pragma unroll
    for (int i = 0; i < 21; ++i) v[i] = A[i];
#pragma unroll
    for (int i = 0; i < 6; ++i) v[21 + i] = g[i];
#pragma unroll
    for (int off = 32; off > 0; off >>= 1) {
#pragma unroll
        for (int i = 0; i < NACC; ++i) v[i] += __shfl_down(v[i], off, 64);
    }
    __shared__ float sred[4][NACC];
    const int wave = threadIdx.x >> 6;
    const int lane = threadIdx.x & 63;
    if (lane == 0) {
#pragma unroll
        for (int i = 0; i < NACC; ++i) sred[wave][i] = v[i];
    }
    __syncthreads();
    if (threadIdx.x < NACC) {
        const float s = sred[0][threadIdx.x] + sred[1][threadIdx.x] +
                        sred[2][threadIdx.x] + sred[3][threadIdx.x];
        atomicAdd(&acc[b * 32 + threadIdx.x], s);
    }
}

__global__ void dba_solve(const float* __restrict__ acc,
                          const float* __restrict__ lmbda,
                          float* __restrict__ pose_out,
                          float* __restrict__ dp_ws, int B)
{
    const int b = blockIdx.x * blockDim.x + threadIdx.x;
    if (b >= B) return;
    float M[6][7];
    const float* a = acc + b * 32;
    int idx = 0;
#pragma unroll
    for (int i = 0; i < 6; ++i) {
#pragma unroll
        for (int j = i; j < 6; ++j) {
            const float t = a[idx++];
            M[i][j] = t;
            M[j][i] = t;
        }
    }
#pragma unroll
    for (int i = 0; i < 6; ++i) M[i][6] = a[21 + i];
    const float lam = lmbda[b];
#pragma unroll
    for (int i = 0; i < 6; ++i) M[i][i] += lam + 0.011f;

    // Gauss-Jordan, no pivoting (matrix strongly diagonally dominant SPD)
#pragma unroll
    for (int k = 0; k < 6; ++k) {
        const float piv = 1.0f / M[k][k];
#pragma unroll
        for (int j = 0; j < 7; ++j) M[k][j] *= piv;
#pragma unroll
        for (int i = 0; i < 6; ++i) {
            if (i == k) continue;
            const float f = M[i][k];
#pragma unroll
            for (int j = 0; j < 7; ++j) M[i][j] -= f * M[k][j];
        }
    }
#pragma unroll
    for (int i = 0; i < 6; ++i) {
        const float x = M[i][6];
        dp_ws[b * 6 + i] = x;                 // UNCLIPPED dp feeds pass 3
        pose_out[b * 6 + i] = fminf(fmaxf(x, -2.0f), 2.0f);
    }
}

__global__ __launch_bounds__(256) void dba_depth_stash(
    const float* __restrict__ stash, const float* __restrict__ dp_ws,
    float* __restrict__ depth_out, int N)
{
    const int b = blockIdx.y;
    float dp[6];
#pragma unroll
    for (int i = 0; i < 6; ++i) dp[i] = dp_ws[b * 6 + i];

    const size_t base = (size_t)b * (size_t)N;
    const int P = N >> 1;
    const int stride = gridDim.x * blockDim.x;
    for (int pr = blockIdx.x * blockDim.x + threadIdx.x; pr < P; pr += stride) {
        const size_t p = base + (size_t)(pr << 1);
        const fv4* sp = (const fv4*)(stash + p * 8);
        const fv4 a0 = sp[0];
        const fv4 a1 = sp[1];
        const fv4 a2 = sp[2];
        const fv4 a3 = sp[3];
        fv2 outv;
        outv.x = a0.x - (a0.y * dp[0] + a0.z * dp[1] + a0.w * dp[2] +
                         a1.x * dp[3] + a1.y * dp[4] + a1.z * dp[5]);
        outv.y = a2.x - (a2.y * dp[0] + a2.z * dp[1] + a2.w * dp[2] +
                         a3.x * dp[3] + a3.y * dp[4] + a3.z * dp[5]);
        __builtin_nontemporal_store(outv, (fv2*)(depth_out + p));
    }
}

// Fallback if ws too small for the stash: recompute from inputs.
__global__ __launch_bounds__(256) void dba_depth_direct(
    const float* __restrict__ r, const float* __restrict__ w,
    const float* __restrict__ J_p, const float* __restrict__ J_d,
    const float* __restrict__ lmbda, const float* __restrict__ dp_ws,
    float* __restrict__ depth_out, int N)
{
    const int b = blockIdx.y;
    const float lam = lmbda[b];
    float dp[6];
#pragma unroll
    for (int i = 0; i < 6; ++i) dp[i] = dp_ws[b * 6 + i];

    const size_t base = (size_t)b * (size_t)N;
    const int P = N >> 1;
    const int stride = gridDim.x * blockDim.x;
    for (int pr = blockIdx.x * blockDim.x + threadIdx.x; pr < P; pr += stride) {
        const size_t p = base + (size_t)(pr << 1);
        const fv4 rv = *(const fv4*)(r + p * 2);
        const fv4 wv = *(const fv4*)(w + p * 2);
        const fv4 jd = *(const fv4*)(J_d + p * 2);
        const fv4* jp = (const fv4*)(J_p + p * 12);
        const fv4 q0 = jp[0];
        const fv4 q1 = jp[1];
        const fv4 q2 = jp[2];
        const fv4 q3 = jp[3];
        const fv4 q4 = jp[4];
        const fv4 q5 = jp[5];
        fv2 outv;
        {
            const float ja[6] = {q0.x, q0.y, q0.z, q0.w, q1.x, q1.y};
            const float jb[6] = {q1.z, q1.w, q2.x, q2.y, q2.z, q2.w};
            float v = 0.f;
#pragma unroll
            for (int i = 0; i < 6; ++i)
                v += (ja[i] * jd.x + jb[i] * jd.y) * dp[i];
            v *= wv.x;
            const float hdd = wv.x * (jd.x * jd.x + jd.y * jd.y);
            const float inv = 1.0f / fmaxf(hdd + lam + wv.y, 1e-4f);
            const float gd  = wv.x * (jd.x * rv.x + jd.y * rv.y);
            outv.x = inv * (gd - v);
        }
        {
            const float ja[6] = {q3.x, q3.y, q3.z, q3.w, q4.x, q4.y};
            const float jb[6] = {q4.z, q4.w, q5.x, q5.y, q5.z, q5.w};
            float v = 0.f;
#pragma unroll
            for (int i = 0; i < 6; ++i)
                v += (ja[i] * jd.z + jb[i] * jd.w) * dp[i];
            v *= wv.z;
            const float hdd = wv.z * (jd.z * jd.z + jd.w * jd.w);
            const float inv = 1.0f / fmaxf(hdd + lam + wv.w, 1e-4f);
            const float gd  = wv.z * (jd.z * rv.z + jd.w * rv.w);
            outv.y = inv * (gd - v);
        }
        *(fv2*)(depth_out + p) = outv;
    }
}

extern "C" void kernel_launch(void* const* d_in, const int* in_sizes, int n_in,
                              void* d_out, int out_size, void* d_ws, size_t ws_size,
                              hipStream_t stream)
{
    const float* r   = (const float*)d_in[0];
    const float* w   = (const float*)d_in[1];
    const float* J_p = (const float*)d_in[2];
    const float* J_d = (const float*)d_in[3];
    const float* lmb = (const float*)d_in[4];
    const int B = in_sizes[4];            // 16
    const int N = in_sizes[0] / (B * 2);  // 196608

    float* acc   = (float*)d_ws;             // B*32 accumulators
    float* dp_ws = (float*)d_ws + B * 32;    // B*6 unclipped dp
    float* stash = (float*)d_ws + 1024;      // 32 B/point stash
    float* out   = (float*)d_out;

    const size_t stash_bytes = (size_t)B * (size_t)N * 8 * sizeof(float);
    const bool use_stash = ws_size >= 4096 + stash_bytes;

    hipMemsetAsync(acc, 0, B * 32 * sizeof(float), stream);

    dim3 grid(192, B);  // 2 pairs/thread
    if (use_stash) {
        dba_reduce_k<true><<<grid, 256, 0, stream>>>(r, w, J_p, J_d, lmb, acc,
                                                     stash, N);
        dba_solve<<<1, 64, 0, stream>>>(acc, lmb, out, dp_ws, B);
        dba_depth_stash<<<grid, 256, 0, stream>>>(stash, dp_ws, out + B * 6, N);
    } else {
        dba_reduce_k<false><<<grid, 256, 0, stream>>>(r, w, J_p, J_d, lmb, acc,
                                                      nullptr, N);
        dba_solve<<<1, 64, 0, stream>>>(acc, lmb, out, dp_ws, B);
        dba_depth_direct<<<grid, 256, 0, stream>>>(r, w, J_p, J_d, lmb, dp_ws,
                                                   out + B * 6, N);
    }
}